// Round 16
// baseline (42.825 us; speedup 1.0000x reference)
//
#include <hip/hip_runtime.h>
#include <math.h>

#define KNBR 20
#define BLK  256
#define GRP  16                 // lanes per atom
#define APB  (BLK / GRP)        // 16 atoms per block-tile
#define MAXP 190                // C(20,2)
#define PERSIST 2048            // 8 blocks/CU * 256 CU
#define GLUT 1024               // gaussian LUT intervals over d in [-1,1]

#define THETA_T  1.9106332362490186f   // 0.6081734479693927 * pi
#define INV_SIG  4.7746482927568605f   // 1 / (12 deg in rad)
#define PI_F     3.14159265358979323846f

// ROUND 16 = DIAGNOSTIC: run the whole persistent body `reps`(=3) times inside
// ONE dispatch so op_kernel (~55us) outranks the harness's 39us ws-poison fills
// in the rocprof top-5 and we finally see VALUBusy/Occupancy/FETCH/conflicts
// for the real body. Writes are identical each rep -> output unchanged.
// asm "+v" on staged indices prevents cross-rep CSE of the restrict-const loads.
__global__ __launch_bounds__(BLK, 4)
void op_kernel(const float* __restrict__ pos,
               const int*   __restrict__ aidx,
               const int*   __restrict__ nidx,
               const int*   __restrict__ vmsk,
               float*       __restrict__ out,
               int M, int NT, int reps)
{
    __shared__ float4 su[APB * KNBR];       // 5120 B
    __shared__ unsigned short lut[MAXP];    // 380 B: ii | (j<<8)
    __shared__ float glut[GLUT + 1];        // 4100 B: gauss(acos(d)) table

    const int tid = threadIdx.x;
    if (tid < MAXP) {
        const int j = (int)((1.0f + sqrtf(fmaf(8.f, (float)tid, 1.0f))) * 0.5f);
        lut[tid] = (unsigned short)((tid - ((j * (j - 1)) >> 1)) | (j << 8));
    }
    for (int k = tid; k <= GLUT; k += BLK) {
        const float d  = fmaf((float)k, 2.0f / GLUT, -1.0f);
        const float dc = fminf(fmaxf(d, -0.9999999f), 0.9999999f);
        const float ad = fabsf(dc);
        const float pq = fmaf(fmaf(fmaf(-0.0187293f, ad, 0.0742610f), ad,
                              -0.2121144f), ad, 1.5707288f) * sqrtf(1.f - ad);
        const float ang = (dc >= 0.f) ? pq : PI_F - pq;
        const float tt = (ang - THETA_T) * INV_SIG;
        glut[k] = __expf(-0.5f * tt * tt);
    }
    __syncthreads();

    const int r   = tid & (GRP - 1);        // lane within 16-lane group
    const int g   = tid / GRP;              // group in block 0..15
    const int sub = (tid & 63) >> 4;        // 16-lane subgroup within wave
    float4* row = &su[g * KNBR];

    for (int rep = 0; rep < reps; ++rep) {
        int t = blockIdx.x;
        if (t >= NT) continue;

        // ---- stage tile t ----
        int i = t * APB + g;
        int is = min(i, M - 1);
        int a  = aidx[is];
        size_t ri = (size_t)is * KNBR;
        int n0 = nidx[ri + r];
        int v0 = (i < M) ? vmsk[ri + r] : 0;
        int n1 = 0, v1 = 0;
        if (r < 4) { n1 = nidx[ri + 16 + r]; v1 = (i < M) ? vmsk[ri + 16 + r] : 0; }
        asm volatile("" : "+v"(a), "+v"(n0), "+v"(v0), "+v"(n1), "+v"(v1));

        while (true) {
            const int tn = t + gridDim.x;
            // ---- prefetch tile tn's indices ----
            int aN = 0, n0N = 0, v0N = 0, n1N = 0, v1N = 0, iN = 0;
            if (tn < NT) {
                iN = tn * APB + g;
                const int isN = min(iN, M - 1);
                aN = aidx[isN];
                const size_t rN = (size_t)isN * KNBR;
                n0N = nidx[rN + r];
                v0N = (iN < M) ? vmsk[rN + r] : 0;
                if (r < 4) { n1N = nidx[rN + 16 + r]; v1N = (iN < M) ? vmsk[rN + 16 + r] : 0; }
            }
            asm volatile("" : "+v"(aN), "+v"(n0N), "+v"(v0N), "+v"(n1N), "+v"(v1N));

            // ---- compute tile t ----
            const int use1 = (r < 4) & (v1 != 0);
            const int s0i = (v0 != 0) ? n0 : 0;
            const int s1i = use1 ? n1 : 0;
            const float cx = pos[3*a], cy = pos[3*a+1], cz = pos[3*a+2];
            const float p0x = pos[3*s0i], p0y = pos[3*s0i+1], p0z = pos[3*s0i+2];
            const float p1x = pos[3*s1i], p1y = pos[3*s1i+1], p1z = pos[3*s1i+2];

            const unsigned long long bal0 = __ballot(v0 != 0);
            const unsigned long long bal1 = __ballot(use1 != 0);
            const unsigned int b16 = (unsigned int)(bal0 >> (sub * 16)) & 0xFFFFu;
            const unsigned int c4  = (unsigned int)(bal1 >> (sub * 16)) & 0xFu;
            const unsigned int mask20 = b16 | (c4 << 16);
            const int total = __popc(mask20);

            if (v0 != 0) {
                const float vx = p0x - cx, vy = p0y - cy, vz = p0z - cz;
                const float d2 = fmaf(vx, vx, fmaf(vy, vy, vz * vz));
                const int   zed = d2 < 1e-24f;
                const float inv = __builtin_amdgcn_rcpf(sqrtf(d2) + 1e-10f);
                const int slot = __popc(mask20 & ((1u << r) - 1u));
                row[slot] = make_float4(zed ? 1.f : vx * inv,
                                        zed ? 0.f : vy * inv,
                                        zed ? 0.f : vz * inv,
                                        zed ? 0.f : 1.f);
            }
            if (use1) {
                const float vx = p1x - cx, vy = p1y - cy, vz = p1z - cz;
                const float d2 = fmaf(vx, vx, fmaf(vy, vy, vz * vz));
                const int   zed = d2 < 1e-24f;
                const float inv = __builtin_amdgcn_rcpf(sqrtf(d2) + 1e-10f);
                const int slot = __popc(mask20 & ((1u << (16 + r)) - 1u));
                row[slot] = make_float4(zed ? 1.f : vx * inv,
                                        zed ? 0.f : vy * inv,
                                        zed ? 0.f : vz * inv,
                                        zed ? 0.f : 1.f);
            }
            // writers == readers (same wave): DS program order, no barrier needed.

            const int npairs = (total * (total - 1)) >> 1;
            float m1 = 0.f, m2 = 0.f, m3 = 0.f, gsum = 0.f;
            for (int p = r; p < npairs; p += GRP) {
                const unsigned short w = lut[p];
                const float4 A = row[w & 0xFF];
                const float4 B = row[w >> 8];
                const float dsh = fmaf(A.x, B.x, fmaf(A.y, B.y, A.z * B.z));
                const float dtt = dsh * A.w * B.w;

                const float e  = dsh * dsh;
                const float e2 = e * e;
                m1 += e;
                m2 += e2;
                m3 = fmaf(e2, e, m3);

                float fx = fmaf(dtt, (float)(GLUT / 2), (float)(GLUT / 2));
                fx = fminf(fmaxf(fx, 0.f), (float)GLUT - 0.0001f);
                const int   k  = (int)fx;
                const float fr = fx - (float)k;
                const float g0 = glut[k];
                const float g1 = glut[k + 1];
                gsum += fmaf(fr, g1 - g0, g0);
            }

#define RED(v) { v += __shfl_xor(v,1); v += __shfl_xor(v,2); \
                 v += __shfl_xor(v,4); v += __shfl_xor(v,8); }
            RED(m1) RED(m2) RED(m3) RED(gsum)
#undef RED

            const float fnp = (float)npairs;
            const float s2 = fmaf(1.5f, m1, -0.5f * fnp);
            const float s4 = fmaf(4.375f, m2, fmaf(-3.75f, m1, 0.375f * fnp));
            const float s6 = fmaf(14.4375f, m3,
                             fmaf(-19.6875f, m2, fmaf(6.5625f, m1, -0.3125f * fnp)));

            const float cn = (float)total;
            const float invnb = 1.f / fmaxf(cn, 1.f);
            const float tet = 2.f * gsum / fmaxf(cn * (cn - 1.f), 1.f);
            const float q2v = invnb * sqrtf(fmaxf(fmaf(2.f, s2, cn), 0.f));
            const float q4v = invnb * sqrtf(fmaxf(fmaf(2.f, s4, cn), 0.f));
            const float q6v = invnb * sqrtf(fmaxf(fmaf(2.f, s6, cn), 0.f));

            float val = cn;
            val = (r == 1) ? tet : val;
            val = (r == 2) ? q2v : val;
            val = (r == 3) ? q4v : val;
            val = (r == 4) ? q6v : val;
            if (r < 5 && i < M)
                out[r * M + i] = val;

            if (tn >= NT) break;
            t = tn; i = iN; a = aN;
            n0 = n0N; v0 = v0N; n1 = n1N; v1 = v1N;
        }
    }
}

extern "C" void kernel_launch(void* const* d_in, const int* in_sizes, int n_in,
                              void* d_out, int out_size, void* d_ws, size_t ws_size,
                              hipStream_t stream) {
    const float* pos  = (const float*)d_in[0];
    const int*   aidx = (const int*)d_in[1];
    const int*   nidx = (const int*)d_in[2];
    const int*   vmsk = (const int*)d_in[3];
    float* out = (float*)d_out;
    const int M = in_sizes[1];
    const int NT = (M + APB - 1) / APB;
    const int grid = NT < PERSIST ? NT : PERSIST;
    op_kernel<<<grid, BLK, 0, stream>>>(pos, aidx, nidx, vmsk, out, M, NT, 3);
}

// Round 17
// 21.282 us; speedup vs baseline: 2.0123x; 2.0123x over previous
//
#include <hip/hip_runtime.h>
#include <math.h>

#define KNBR 20
#define BLK  256
#define GRP  16                 // lanes per atom
#define APB  (BLK / GRP)        // 16 atoms per block-tile
#define MAXP 190                // C(20,2)
#define PERSIST 2048            // 8 blocks/CU * 256 CU
#define GLUT 1024               // gaussian LUT intervals over d in [-1,1]

#define THETA_T  1.9106332362490186f   // 0.6081734479693927 * pi
#define INV_SIG  4.7746482927568605f   // 1 / (12 deg in rad)
#define PI_F     3.14159265358979323846f

typedef float float4a __attribute__((ext_vector_type(4), aligned(4)));

// One-instruction float3 gather: global_load_dwordx4 at 4B-aligned 3n,
// clamped at the buffer end (shift-select when the 16B window would overrun).
__device__ __forceinline__ void ldpos(const float* __restrict__ pos, int n, int lim,
                                      float& x, float& y, float& z) {
    const int base = 3 * n;
    const int nc = base > lim ? lim : base;     // lim = 3N-4
    const float4a v = *reinterpret_cast<const float4a*>(pos + nc);
    const bool sh = nc != base;                 // only when n == N-1
    x = sh ? v.y : v.x;
    y = sh ? v.z : v.y;
    z = sh ? v.w : v.z;
}

__device__ __forceinline__ float gauss_at(int k) {
    const float d  = fmaf((float)k, 2.0f / GLUT, -1.0f);
    const float dc = fminf(fmaxf(d, -0.9999999f), 0.9999999f);
    const float ad = fabsf(dc);
    const float pq = fmaf(fmaf(fmaf(-0.0187293f, ad, 0.0742610f), ad,
                          -0.2121144f), ad, 1.5707288f) * sqrtf(1.f - ad);
    const float ang = (dc >= 0.f) ? pq : PI_F - pq;
    const float tt = (ang - THETA_T) * INV_SIG;
    return __expf(-0.5f * tt * tt);
}

// VALU-bound per R16 counters (VALUBusy 89%) -> this round cuts issue count:
// EXACT template removes all bound guards; int32 offsets remove 64-bit muls;
// dwordx4 gathers remove 2/3 of gather address math; packed glut halves LUT ops.
template<bool EXACT>
__global__ __launch_bounds__(BLK, 4)
void op_kernel(const float* __restrict__ pos,
               const int*   __restrict__ aidx,
               const int*   __restrict__ nidx,
               const int*   __restrict__ vmsk,
               float*       __restrict__ out,
               int M, int N, int NT)
{
    __shared__ float4 su[APB * KNBR];       // 5120 B
    __shared__ unsigned short lut[MAXP];    // 380 B: ii | (j<<8)
    __shared__ float2 glut[GLUT];           // 8192 B: (g[k], g[k+1]) per node

    const int tid = threadIdx.x;
    if (tid < MAXP) {
        const int j = (int)((1.0f + sqrtf(fmaf(8.f, (float)tid, 1.0f))) * 0.5f);
        lut[tid] = (unsigned short)((tid - ((j * (j - 1)) >> 1)) | (j << 8));
    }
    for (int k = tid; k < GLUT; k += BLK)
        glut[k] = make_float2(gauss_at(k), gauss_at(k + 1));
    __syncthreads();

    const int r   = tid & (GRP - 1);        // lane within 16-lane group
    const int g   = tid / GRP;              // group in block 0..15
    const int sub = (tid & 63) >> 4;        // 16-lane subgroup within wave
    const int lim = 3 * N - 4;
    float4* row = &su[g * KNBR];

    int t = blockIdx.x;
    if (t >= NT) return;

    // ---- stage tile t (int32 offsets throughout) ----
    int i = t * APB + g;
    int is = EXACT ? i : min(i, M - 1);
    int a  = aidx[is];
    int ri = is * KNBR;
    int n0 = nidx[ri + r];
    int v0 = (EXACT || i < M) ? vmsk[ri + r] : 0;
    int n1 = 0, v1 = 0;
    if (r < 4) { n1 = nidx[ri + 16 + r]; v1 = (EXACT || i < M) ? vmsk[ri + 16 + r] : 0; }

    while (true) {
        const int tn = t + gridDim.x;
        // ---- prefetch tile tn's indices (hides HBM latency under compute) ----
        int aN = 0, n0N = 0, v0N = 0, n1N = 0, v1N = 0, iN = 0;
        if (tn < NT) {
            iN = tn * APB + g;
            const int isN = EXACT ? iN : min(iN, M - 1);
            aN = aidx[isN];
            const int rN = isN * KNBR;
            n0N = nidx[rN + r];
            v0N = (EXACT || iN < M) ? vmsk[rN + r] : 0;
            if (r < 4) { n1N = nidx[rN + 16 + r]; v1N = (EXACT || iN < M) ? vmsk[rN + 16 + r] : 0; }
        }

        // ---- compute tile t ----
        const int use1 = (r < 4) & (v1 != 0);
        const int s0i = (v0 != 0) ? n0 : 0;
        const int s1i = use1 ? n1 : 0;
        float cx, cy, cz, p0x, p0y, p0z, p1x, p1y, p1z;
        ldpos(pos, a,   lim, cx,  cy,  cz);
        ldpos(pos, s0i, lim, p0x, p0y, p0z);
        ldpos(pos, s1i, lim, p1x, p1y, p1z);

        const unsigned long long bal0 = __ballot(v0 != 0);
        const unsigned long long bal1 = __ballot(use1 != 0);
        const unsigned int b16 = (unsigned int)(bal0 >> (sub * 16)) & 0xFFFFu;
        const unsigned int c4  = (unsigned int)(bal1 >> (sub * 16)) & 0xFu;
        const unsigned int mask20 = b16 | (c4 << 16);
        const int total = __popc(mask20);

        if (v0 != 0) {
            const float vx = p0x - cx, vy = p0y - cy, vz = p0z - cz;
            const float d2 = fmaf(vx, vx, fmaf(vy, vy, vz * vz));
            const int   zed = d2 < 1e-24f;
            const float inv = __builtin_amdgcn_rcpf(sqrtf(d2) + 1e-10f);
            const int slot = __popc(mask20 & ((1u << r) - 1u));
            row[slot] = make_float4(zed ? 1.f : vx * inv,
                                    zed ? 0.f : vy * inv,
                                    zed ? 0.f : vz * inv,
                                    zed ? 0.f : 1.f);
        }
        if (use1) {
            const float vx = p1x - cx, vy = p1y - cy, vz = p1z - cz;
            const float d2 = fmaf(vx, vx, fmaf(vy, vy, vz * vz));
            const int   zed = d2 < 1e-24f;
            const float inv = __builtin_amdgcn_rcpf(sqrtf(d2) + 1e-10f);
            const int slot = __popc(mask20 & ((1u << (16 + r)) - 1u));
            row[slot] = make_float4(zed ? 1.f : vx * inv,
                                    zed ? 0.f : vy * inv,
                                    zed ? 0.f : vz * inv,
                                    zed ? 0.f : 1.f);
        }
        // writers == readers (same wave): DS program order, no barrier needed.

        const int npairs = (total * (total - 1)) >> 1;
        float m1 = 0.f, m2 = 0.f, m3 = 0.f, gsum = 0.f;
        for (int p = r; p < npairs; p += GRP) {
            const unsigned short w = lut[p];
            const float4 A = row[w & 0xFF];
            const float4 B = row[w >> 8];
            const float dsh = fmaf(A.x, B.x, fmaf(A.y, B.y, A.z * B.z));
            const float dtt = dsh * A.w * B.w;

            const float e  = dsh * dsh;
            const float e2 = e * e;
            m1 += e;
            m2 += e2;
            m3 = fmaf(e2, e, m3);

            // gaussian via packed LUT node + lerp (one ds_read_b64)
            float fx = fmaf(dtt, (float)(GLUT / 2), (float)(GLUT / 2));
            fx = fminf(fmaxf(fx, 0.f), (float)GLUT - 0.001f);
            const int   k  = (int)fx;
            const float fr = fx - (float)k;
            const float2 gg = glut[k];
            gsum += fmaf(fr, gg.y - gg.x, gg.x);
        }

#define RED(v) { v += __shfl_xor(v,1); v += __shfl_xor(v,2); \
                 v += __shfl_xor(v,4); v += __shfl_xor(v,8); }
        RED(m1) RED(m2) RED(m3) RED(gsum)
#undef RED

        const float fnp = (float)npairs;
        const float s2 = fmaf(1.5f, m1, -0.5f * fnp);
        const float s4 = fmaf(4.375f, m2, fmaf(-3.75f, m1, 0.375f * fnp));
        const float s6 = fmaf(14.4375f, m3,
                         fmaf(-19.6875f, m2, fmaf(6.5625f, m1, -0.3125f * fnp)));

        const float cn = (float)total;
        const float invnb = 1.f / fmaxf(cn, 1.f);
        const float tet = 2.f * gsum / fmaxf(cn * (cn - 1.f), 1.f);
        const float q2v = invnb * sqrtf(fmaxf(fmaf(2.f, s2, cn), 0.f));
        const float q4v = invnb * sqrtf(fmaxf(fmaf(2.f, s4, cn), 0.f));
        const float q6v = invnb * sqrtf(fmaxf(fmaf(2.f, s6, cn), 0.f));

        float val = cn;
        val = (r == 1) ? tet : val;
        val = (r == 2) ? q2v : val;
        val = (r == 3) ? q4v : val;
        val = (r == 4) ? q6v : val;
        if (r < 5 && (EXACT || i < M))
            out[r * M + i] = val;

        if (tn >= NT) break;
        t = tn; i = iN; a = aN;
        n0 = n0N; v0 = v0N; n1 = n1N; v1 = v1N;
    }
}

extern "C" void kernel_launch(void* const* d_in, const int* in_sizes, int n_in,
                              void* d_out, int out_size, void* d_ws, size_t ws_size,
                              hipStream_t stream) {
    const float* pos  = (const float*)d_in[0];
    const int*   aidx = (const int*)d_in[1];
    const int*   nidx = (const int*)d_in[2];
    const int*   vmsk = (const int*)d_in[3];
    float* out = (float*)d_out;
    const int N = in_sizes[0] / 3;
    const int M = in_sizes[1];
    const int NT = (M + APB - 1) / APB;
    const int grid = NT < PERSIST ? NT : PERSIST;
    if (M % APB == 0)
        op_kernel<true><<<grid, BLK, 0, stream>>>(pos, aidx, nidx, vmsk, out, M, N, NT);
    else
        op_kernel<false><<<grid, BLK, 0, stream>>>(pos, aidx, nidx, vmsk, out, M, N, NT);
}

// Round 18
// 16.724 us; speedup vs baseline: 2.5607x; 1.2726x over previous
//
#include <hip/hip_runtime.h>
#include <math.h>

#define KNBR 20
#define BLK  256
#define GRP  8                  // lanes per atom
#define APB  (BLK / GRP)        // 32 atoms per block-tile
#define MAXP 190                // C(20,2)
#define PERSIST 2048            // 8 blocks/CU * 256 CU
#define GLUT 1024               // gaussian LUT intervals over d in [-1,1]

#define THETA_T  1.9106332362490186f   // 0.6081734479693927 * pi
#define INV_SIG  4.7746482927568605f   // 1 / (12 deg in rad)
#define PI_F     3.14159265358979323846f

__device__ __forceinline__ float gauss_at(int k) {
    const float d  = fmaf((float)k, 2.0f / GLUT, -1.0f);
    const float dc = fminf(fmaxf(d, -0.9999999f), 0.9999999f);
    const float ad = fabsf(dc);
    const float pq = fmaf(fmaf(fmaf(-0.0187293f, ad, 0.0742610f), ad,
                          -0.2121144f), ad, 1.5707288f) * sqrtf(1.f - ad);
    const float ang = (dc >= 0.f) ? pq : PI_F - pq;
    const float tt = (ang - THETA_T) * INV_SIG;
    return __expf(-0.5f * tt * tt);
}

// R18 vs R13 (19.6us): GRP 16->8 halves per-atom fixed costs (R16: VALU-bound
// at 89%, fixed costs dominate); rcpf replaces 2 IEEE divides; nearest-neighbor
// LUT drops the lerp. Pair-loop cost/atom is GRP-invariant, fixed costs aren't.
template<bool EXACT>
__global__ __launch_bounds__(BLK, 8)
void op_kernel(const float* __restrict__ pos,
               const int*   __restrict__ aidx,
               const int*   __restrict__ nidx,
               const int*   __restrict__ vmsk,
               float*       __restrict__ out,
               int M, int NT)
{
    __shared__ float4 su[APB * KNBR];       // 10240 B
    __shared__ unsigned short lut[MAXP];    // 380 B: ii | (j<<8)
    __shared__ float glut[GLUT + 1];        // 4100 B: gauss(acos(d)) table

    const int tid = threadIdx.x;
    if (tid < MAXP) {
        const int j = (int)((1.0f + sqrtf(fmaf(8.f, (float)tid, 1.0f))) * 0.5f);
        lut[tid] = (unsigned short)((tid - ((j * (j - 1)) >> 1)) | (j << 8));
    }
    for (int k = tid; k <= GLUT; k += BLK)
        glut[k] = gauss_at(k);
    __syncthreads();

    const int r   = tid & (GRP - 1);        // lane within 8-lane group
    const int g   = tid / GRP;              // group in block 0..31
    const int sub = (tid & 63) >> 3;        // 8-lane subgroup within wave 0..7
    float4* row = &su[g * KNBR];

    int t = blockIdx.x;
    if (t >= NT) return;

    // ---- stage tile t (lane r owns slots r, r+8, and r<4: 16+r) ----
    int i = t * APB + g;
    int is = EXACT ? i : min(i, M - 1);
    int a  = aidx[is];
    int ri = is * KNBR;
    int n0 = nidx[ri + r];
    int v0 = (EXACT || i < M) ? vmsk[ri + r] : 0;
    int n1 = nidx[ri + 8 + r];
    int v1 = (EXACT || i < M) ? vmsk[ri + 8 + r] : 0;
    int n2 = 0, v2 = 0;
    if (r < 4) { n2 = nidx[ri + 16 + r]; v2 = (EXACT || i < M) ? vmsk[ri + 16 + r] : 0; }

    while (true) {
        const int tn = t + gridDim.x;
        // ---- prefetch tile tn's indices (hides HBM latency under compute) ----
        int aN = 0, n0N = 0, v0N = 0, n1N = 0, v1N = 0, n2N = 0, v2N = 0, iN = 0;
        if (tn < NT) {
            iN = tn * APB + g;
            const int isN = EXACT ? iN : min(iN, M - 1);
            aN = aidx[isN];
            const int rN = isN * KNBR;
            n0N = nidx[rN + r];
            v0N = (EXACT || iN < M) ? vmsk[rN + r] : 0;
            n1N = nidx[rN + 8 + r];
            v1N = (EXACT || iN < M) ? vmsk[rN + 8 + r] : 0;
            if (r < 4) { n2N = nidx[rN + 16 + r]; v2N = (EXACT || iN < M) ? vmsk[rN + 16 + r] : 0; }
        }

        // ---- compute tile t ----
        const int use2 = (r < 4) & (v2 != 0);
        const int s0i = (v0 != 0) ? n0 : 0;
        const int s1i = (v1 != 0) ? n1 : 0;
        const int s2i = use2 ? n2 : 0;
        const float cx  = pos[3*a],   cy  = pos[3*a+1],   cz  = pos[3*a+2];
        const float p0x = pos[3*s0i], p0y = pos[3*s0i+1], p0z = pos[3*s0i+2];
        const float p1x = pos[3*s1i], p1y = pos[3*s1i+1], p1z = pos[3*s1i+2];
        const float p2x = pos[3*s2i], p2y = pos[3*s2i+1], p2z = pos[3*s2i+2];

        const unsigned long long bal0 = __ballot(v0 != 0);
        const unsigned long long bal1 = __ballot(v1 != 0);
        const unsigned long long bal2 = __ballot(use2 != 0);
        const unsigned int b0 = (unsigned int)(bal0 >> (sub * 8)) & 0xFFu;
        const unsigned int b1 = (unsigned int)(bal1 >> (sub * 8)) & 0xFFu;
        const unsigned int b2 = (unsigned int)(bal2 >> (sub * 8)) & 0xFu;
        const unsigned int mask20 = b0 | (b1 << 8) | (b2 << 16);
        const int total = __popc(mask20);

        if (v0 != 0) {
            const float vx = p0x - cx, vy = p0y - cy, vz = p0z - cz;
            const float d2 = fmaf(vx, vx, fmaf(vy, vy, vz * vz));
            const int   zed = d2 < 1e-24f;
            const float inv = __builtin_amdgcn_rcpf(sqrtf(d2) + 1e-10f);
            const int slot = __popc(mask20 & ((1u << r) - 1u));
            row[slot] = make_float4(zed ? 1.f : vx * inv,
                                    zed ? 0.f : vy * inv,
                                    zed ? 0.f : vz * inv,
                                    zed ? 0.f : 1.f);
        }
        if (v1 != 0) {
            const float vx = p1x - cx, vy = p1y - cy, vz = p1z - cz;
            const float d2 = fmaf(vx, vx, fmaf(vy, vy, vz * vz));
            const int   zed = d2 < 1e-24f;
            const float inv = __builtin_amdgcn_rcpf(sqrtf(d2) + 1e-10f);
            const int slot = __popc(mask20 & ((1u << (8 + r)) - 1u));
            row[slot] = make_float4(zed ? 1.f : vx * inv,
                                    zed ? 0.f : vy * inv,
                                    zed ? 0.f : vz * inv,
                                    zed ? 0.f : 1.f);
        }
        if (use2) {
            const float vx = p2x - cx, vy = p2y - cy, vz = p2z - cz;
            const float d2 = fmaf(vx, vx, fmaf(vy, vy, vz * vz));
            const int   zed = d2 < 1e-24f;
            const float inv = __builtin_amdgcn_rcpf(sqrtf(d2) + 1e-10f);
            const int slot = __popc(mask20 & ((1u << (16 + r)) - 1u));
            row[slot] = make_float4(zed ? 1.f : vx * inv,
                                    zed ? 0.f : vy * inv,
                                    zed ? 0.f : vz * inv,
                                    zed ? 0.f : 1.f);
        }
        // writers == readers (same wave): DS program order, no barrier needed.

        const int npairs = (total * (total - 1)) >> 1;
        float m1 = 0.f, m2 = 0.f, m3 = 0.f, gsum = 0.f;
        for (int p = r; p < npairs; p += GRP) {
            const unsigned short w = lut[p];
            const float4 A = row[w & 0xFF];
            const float4 B = row[w >> 8];
            const float dsh = fmaf(A.x, B.x, fmaf(A.y, B.y, A.z * B.z));
            const float dtt = dsh * A.w * B.w;

            const float e  = dsh * dsh;
            const float e2 = e * e;
            m1 += e;
            m2 += e2;
            m3 = fmaf(e2, e, m3);

            // gaussian via nearest-neighbor LUT (err <= ~3.3e-3)
            float fx = fmaf(dtt, (float)(GLUT / 2), (float)(GLUT / 2) + 0.5f);
            fx = fminf(fmaxf(fx, 0.f), (float)GLUT + 0.49f);
            gsum += glut[(int)fx];
        }

#define RED(v) { v += __shfl_xor(v,1); v += __shfl_xor(v,2); v += __shfl_xor(v,4); }
        RED(m1) RED(m2) RED(m3) RED(gsum)
#undef RED

        const float fnp = (float)npairs;
        const float s2 = fmaf(1.5f, m1, -0.5f * fnp);
        const float s4 = fmaf(4.375f, m2, fmaf(-3.75f, m1, 0.375f * fnp));
        const float s6 = fmaf(14.4375f, m3,
                         fmaf(-19.6875f, m2, fmaf(6.5625f, m1, -0.3125f * fnp)));

        const float cn = (float)total;
        const float invnb = __builtin_amdgcn_rcpf(fmaxf(cn, 1.f));
        const float tet = gsum * __builtin_amdgcn_rcpf(fmaxf(fnp, 0.5f));
        const float q2v = invnb * sqrtf(fmaxf(fmaf(2.f, s2, cn), 0.f));
        const float q4v = invnb * sqrtf(fmaxf(fmaf(2.f, s4, cn), 0.f));
        const float q6v = invnb * sqrtf(fmaxf(fmaf(2.f, s6, cn), 0.f));

        float val = cn;
        val = (r == 1) ? tet : val;
        val = (r == 2) ? q2v : val;
        val = (r == 3) ? q4v : val;
        val = (r == 4) ? q6v : val;
        if (r < 5 && (EXACT || i < M))
            out[r * M + i] = val;

        if (tn >= NT) break;
        t = tn; i = iN; a = aN;
        n0 = n0N; v0 = v0N; n1 = n1N; v1 = v1N; n2 = n2N; v2 = v2N;
    }
}

extern "C" void kernel_launch(void* const* d_in, const int* in_sizes, int n_in,
                              void* d_out, int out_size, void* d_ws, size_t ws_size,
                              hipStream_t stream) {
    const float* pos  = (const float*)d_in[0];
    const int*   aidx = (const int*)d_in[1];
    const int*   nidx = (const int*)d_in[2];
    const int*   vmsk = (const int*)d_in[3];
    float* out = (float*)d_out;
    const int M = in_sizes[1];
    const int NT = (M + APB - 1) / APB;
    const int grid = NT < PERSIST ? NT : PERSIST;
    if (M % APB == 0)
        op_kernel<true><<<grid, BLK, 0, stream>>>(pos, aidx, nidx, vmsk, out, M, NT);
    else
        op_kernel<false><<<grid, BLK, 0, stream>>>(pos, aidx, nidx, vmsk, out, M, NT);
}